// Round 1
// baseline (444.900 us; speedup 1.0000x reference)
//
#include <hip/hip_runtime.h>
#include <hip/hip_bf16.h>

#define N_BOXES 8192
#define NW 128            // number of 64-box chunks / 64-bit words per row
#define FEAT 10

typedef unsigned long long u64;
typedef unsigned int u32;

// ---------------- Phase A: rank + scatter sorted boxes ----------------
// Descending-score order with ties broken by larger original index first
// (matches jnp.argsort(stable)[::-1]).
// grid 256 blocks x 256 threads; each block handles 32 boxes, 8 threads/box.
__global__ void rank_scatter_kernel(const float* __restrict__ bboxes,
                                    const float* __restrict__ scores,
                                    float* __restrict__ x1s, float* __restrict__ y1s,
                                    float* __restrict__ x2s, float* __restrict__ y2s,
                                    float* __restrict__ areas, u32* __restrict__ rank_of) {
    __shared__ float sc[N_BOXES];
    int tid = threadIdx.x;
    for (int t = 0; t < N_BOXES / 256; ++t)
        sc[tid + 256 * t] = scores[tid + 256 * t];
    __syncthreads();
    int k = tid >> 3;          // box slot 0..31
    int s = tid & 7;           // segment 0..7
    int i = blockIdx.x * 32 + k;
    float si = sc[i];
    int cnt = 0;
    int j0 = s * (N_BOXES / 8);
    #pragma unroll 8
    for (int j = j0; j < j0 + N_BOXES / 8; ++j) {
        float sj = sc[j];
        cnt += (int)((sj > si) || (sj == si && j > i));
    }
    cnt += __shfl_down(cnt, 4, 8);
    cnt += __shfl_down(cnt, 2, 8);
    cnt += __shfl_down(cnt, 1, 8);
    if (s == 0) {
        int r = cnt;
        float x = bboxes[4 * i + 0], y = bboxes[4 * i + 1];
        float w = bboxes[4 * i + 2], h = bboxes[4 * i + 3];
        float x2 = x + w, y2 = y + h;           // exact ref op order
        float ar = (x2 - x) * (y2 - y);         // exact ref op order
        x1s[r] = x; y1s[r] = y; x2s[r] = x2; y2s[r] = y2; areas[r] = ar;
        rank_of[i] = (u32)r;
    }
}

// ---------------- Phase B: suppression bitmask matrix ----------------
// Column-major: MT[(size_t)cj*N_BOXES + i] = 64-bit word over j in chunk cj
// for sorted row i.  Bit set iff iou(i,j) > 0.5 and j > i (sorted order).
// Grid (128,128) of 64-thread blocks, upper triangle only.
__global__ void mask_kernel(const float* __restrict__ x1s, const float* __restrict__ y1s,
                            const float* __restrict__ x2s, const float* __restrict__ y2s,
                            const float* __restrict__ areas, u64* __restrict__ MT) {
    int ci = blockIdx.x, cj = blockIdx.y;
    if (cj < ci) return;
    int lane = threadIdx.x;    // 0..63
    __shared__ float sx1[64], sy1[64], sx2[64], sy2[64], sar[64];
    int ig0 = ci * 64;
    sx1[lane] = x1s[ig0 + lane]; sy1[lane] = y1s[ig0 + lane];
    sx2[lane] = x2s[ig0 + lane]; sy2[lane] = y2s[ig0 + lane];
    sar[lane] = areas[ig0 + lane];
    __syncthreads();
    int jg = cj * 64 + lane;
    float jx1 = x1s[jg], jy1 = y1s[jg], jx2 = x2s[jg], jy2 = y2s[jg], jar = areas[jg];
    u64 my = 0;
    for (int ip = 0; ip < 64; ++ip) {
        int ig = ig0 + ip;
        float xx1 = fmaxf(sx1[ip], jx1);
        float yy1 = fmaxf(sy1[ip], jy1);
        float xx2 = fminf(sx2[ip], jx2);
        float yy2 = fminf(sy2[ip], jy2);
        float iw = fmaxf(xx2 - xx1, 0.0f);
        float ih = fmaxf(yy2 - yy1, 0.0f);
        float inter = iw * ih;
        float uni = sar[ip] + jar - inter;
        float iou = __fdiv_rn(inter, uni);      // IEEE-exact like numpy
        bool sup = (iou > 0.5f) && (jg > ig);
        u64 w = __ballot(sup);
        if (lane == ip) my = w;
    }
    MT[(size_t)cj * N_BOXES + ig0 + lane] = my;
}

// ---------------- Phase C: sequential greedy reduce (1 block) ----------------
__global__ void __launch_bounds__(1024) nms_reduce_kernel(const u64* __restrict__ MT,
                                                          u64* __restrict__ keepw_g) {
    __shared__ u64 removed[NW];
    __shared__ u64 cur_kept;
    int tid = threadIdx.x;
    if (tid < NW) removed[tid] = 0;
    __syncthreads();
    u64 dw = 0;
    if (tid < 64) dw = MT[(size_t)0 * N_BOXES + tid];   // diag words for chunk 0
    for (int c = 0; c < NW; ++c) {
        if (tid < 64) {
            u64 alive = ~removed[c];
            u64 kept = 0;
            u64 d = dw;
            while (alive) {
                int ip = __builtin_ctzll(alive);
                kept |= (1ull << ip);
                unsigned lo = __shfl((unsigned)(d & 0xffffffffull), ip, 64);
                unsigned hi = __shfl((unsigned)(d >> 32), ip, 64);
                u64 m = ((u64)hi << 32) | (u64)lo;
                alive &= ~(m | (1ull << ip));
            }
            if (tid == 0) { cur_kept = kept; keepw_g[c] = kept; }
        }
        __syncthreads();
        u64 kept = cur_kept;
        // prefetch next chunk's diagonal words (wave0)
        if (tid < 64 && c + 1 < NW)
            dw = MT[(size_t)(c + 1) * N_BOXES + (size_t)(c + 1) * 64 + tid];
        // OR kept rows of chunk c into all future removed words
        int wrel = tid >> 3, s = tid & 7;
        int w = c + 1 + wrel;
        if (w < NW && kept) {
            u64 acc = 0;
            const u64* col = MT + (size_t)w * N_BOXES + (size_t)c * 64;
            #pragma unroll
            for (int kk = 0; kk < 8; ++kk) {
                int r = s + 8 * kk;
                if ((kept >> r) & 1ull) acc |= col[r];
            }
            #pragma unroll
            for (int dlt = 4; dlt >= 1; dlt >>= 1) {
                unsigned lo = __shfl_xor((unsigned)(acc & 0xffffffffull), dlt, 8);
                unsigned hi = __shfl_xor((unsigned)(acc >> 32), dlt, 8);
                acc |= ((u64)hi << 32) | (u64)lo;
            }
            if (s == 0 && acc) removed[w] |= acc;
        }
        __syncthreads();
    }
}

// ---------------- Phase D: regression + masked output ----------------
__global__ void output_kernel(const float* __restrict__ bboxes,
                              const float* __restrict__ features,
                              const float* __restrict__ Wm, const float* __restrict__ bv,
                              const int* __restrict__ widthp, const int* __restrict__ heightp,
                              const u32* __restrict__ rank_of, const u64* __restrict__ keepw,
                              float* __restrict__ out) {
    int i = blockIdx.x * blockDim.x + threadIdx.x;
    if (i >= N_BOXES) return;
    u32 r = rank_of[i];
    float keep = (float)((keepw[r >> 6] >> (r & 63)) & 1ull);
    float z0 = bv[0], z1 = bv[1], z2 = bv[2], z3 = bv[3];
    #pragma unroll
    for (int m = 0; m < FEAT; ++m) {
        float f = features[i * FEAT + m];
        z0 += f * Wm[m * 4 + 0];
        z1 += f * Wm[m * 4 + 1];
        z2 += f * Wm[m * 4 + 2];
        z3 += f * Wm[m * 4 + 3];
    }
    float t0 = 1.0f / (1.0f + expf(-z0));
    float t1 = 1.0f / (1.0f + expf(-z1));
    float t2 = 1.0f / (1.0f + expf(-z2));
    float t3 = 1.0f / (1.0f + expf(-z3));
    float x = bboxes[4 * i + 0], y = bboxes[4 * i + 1];
    float w = bboxes[4 * i + 2], h = bboxes[4 * i + 3];
    float ox = fmaxf(t0 * w + x, 0.0f);
    float oy = fmaxf(t1 * h + y, 0.0f);
    float ow = w * expf(t2);
    float oh = h * expf(t3);
    float sw = (float)(*widthp), sh = (float)(*heightp);
    out[4 * i + 0] = ox * sw * keep;
    out[4 * i + 1] = oy * sh * keep;
    out[4 * i + 2] = ow * sw * keep;
    out[4 * i + 3] = oh * sh * keep;
}

extern "C" void kernel_launch(void* const* d_in, const int* in_sizes, int n_in,
                              void* d_out, int out_size, void* d_ws, size_t ws_size,
                              hipStream_t stream) {
    const float* bboxes   = (const float*)d_in[0];
    const float* scores   = (const float*)d_in[1];
    const float* features = (const float*)d_in[2];
    const float* Wm       = (const float*)d_in[3];
    const float* bv       = (const float*)d_in[4];
    const int*   widthp   = (const int*)d_in[5];
    const int*   heightp  = (const int*)d_in[6];
    float* out = (float*)d_out;

    char* ws = (char*)d_ws;
    u64* MT      = (u64*)ws;                                      // 8 MiB
    float* x1s   = (float*)(ws + (size_t)NW * N_BOXES * sizeof(u64));
    float* y1s   = x1s + N_BOXES;
    float* x2s   = y1s + N_BOXES;
    float* y2s   = x2s + N_BOXES;
    float* areas = y2s + N_BOXES;
    u32* rank_of = (u32*)(areas + N_BOXES);
    u64* keepw   = (u64*)(rank_of + N_BOXES);

    rank_scatter_kernel<<<N_BOXES / 32, 256, 0, stream>>>(bboxes, scores,
                                                          x1s, y1s, x2s, y2s, areas, rank_of);
    mask_kernel<<<dim3(NW, NW), 64, 0, stream>>>(x1s, y1s, x2s, y2s, areas, MT);
    nms_reduce_kernel<<<1, 1024, 0, stream>>>(MT, keepw);
    output_kernel<<<N_BOXES / 256, 256, 0, stream>>>(bboxes, features, Wm, bv,
                                                     widthp, heightp, rank_of, keepw, out);
}

// Round 2
// 326.996 us; speedup vs baseline: 1.3606x; 1.3606x over previous
//
#include <hip/hip_runtime.h>
#include <hip/hip_bf16.h>

#define N_BOXES 8192
#define NW 128            // number of 64-box chunks / 64-bit words per row
#define FEAT 10

typedef unsigned long long u64;
typedef unsigned int u32;

// Transposed near-diagonal words live in MT's unused lower-triangle region.
// TR[d][j] (d = cj-ci in {0,1,2}) = word over i in chunk (jchunk-d) of sup(i->j).
// Word w's used (upper-tri) region is i < (w+1)*64, so indices >=256 of words
// 0..2 and indices 256..1023 of word 3 are free.
__host__ __device__ inline size_t tr_addr(int d, int j) {
    return (j >= 256) ? ((size_t)d * N_BOXES + j)
                      : ((size_t)3 * N_BOXES + 256 + d * 256 + j);
}

// ---------------- Phase A: rank + scatter sorted boxes ----------------
__global__ void rank_scatter_kernel(const float* __restrict__ bboxes,
                                    const float* __restrict__ scores,
                                    float* __restrict__ x1s, float* __restrict__ y1s,
                                    float* __restrict__ x2s, float* __restrict__ y2s,
                                    float* __restrict__ areas, u32* __restrict__ rank_of) {
    __shared__ float sc[N_BOXES];
    int tid = threadIdx.x;
    for (int t = 0; t < N_BOXES / 256; ++t)
        sc[tid + 256 * t] = scores[tid + 256 * t];
    __syncthreads();
    int k = tid >> 3;          // box slot 0..31
    int s = tid & 7;           // segment 0..7
    int i = blockIdx.x * 32 + k;
    float si = sc[i];
    int cnt = 0;
    int j0 = s * (N_BOXES / 8);
    #pragma unroll 8
    for (int j = j0; j < j0 + N_BOXES / 8; ++j) {
        float sj = sc[j];
        cnt += (int)((sj > si) || (sj == si && j > i));
    }
    cnt += __shfl_down(cnt, 4, 8);
    cnt += __shfl_down(cnt, 2, 8);
    cnt += __shfl_down(cnt, 1, 8);
    if (s == 0) {
        int r = cnt;
        float x = bboxes[4 * i + 0], y = bboxes[4 * i + 1];
        float w = bboxes[4 * i + 2], h = bboxes[4 * i + 3];
        float x2 = x + w, y2 = y + h;           // exact ref op order
        float ar = (x2 - x) * (y2 - y);         // exact ref op order
        x1s[r] = x; y1s[r] = y; x2s[r] = x2; y2s[r] = y2; areas[r] = ar;
        rank_of[i] = (u32)r;
    }
}

// ---------------- Phase B: suppression bitmask matrix ----------------
// MT[(size_t)cj*N_BOXES + i]: bits over j in chunk cj, row i (sup(i->j), j>i).
// Near-diagonal blocks also emit transposed words (suppressors of j) into the
// free lower-triangle region via tr_addr().
__global__ void mask_kernel(const float* __restrict__ x1s, const float* __restrict__ y1s,
                            const float* __restrict__ x2s, const float* __restrict__ y2s,
                            const float* __restrict__ areas, u64* __restrict__ MT) {
    int ci = blockIdx.x, cj = blockIdx.y;
    if (cj < ci) return;
    int lane = threadIdx.x;    // 0..63
    __shared__ float sx1[64], sy1[64], sx2[64], sy2[64], sar[64];
    int ig0 = ci * 64;
    sx1[lane] = x1s[ig0 + lane]; sy1[lane] = y1s[ig0 + lane];
    sx2[lane] = x2s[ig0 + lane]; sy2[lane] = y2s[ig0 + lane];
    sar[lane] = areas[ig0 + lane];
    __syncthreads();
    int jg = cj * 64 + lane;
    float jx1 = x1s[jg], jy1 = y1s[jg], jx2 = x2s[jg], jy2 = y2s[jg], jar = areas[jg];
    u64 my = 0;        // row word for row ig0+lane
    u64 cw = 0;        // column (transposed) word for box jg
    for (int ip = 0; ip < 64; ++ip) {
        int ig = ig0 + ip;
        float xx1 = fmaxf(sx1[ip], jx1);
        float yy1 = fmaxf(sy1[ip], jy1);
        float xx2 = fminf(sx2[ip], jx2);
        float yy2 = fminf(sy2[ip], jy2);
        float iw = fmaxf(xx2 - xx1, 0.0f);
        float ih = fmaxf(yy2 - yy1, 0.0f);
        float inter = iw * ih;
        float uni = sar[ip] + jar - inter;
        float iou = __fdiv_rn(inter, uni);      // IEEE-exact like numpy
        bool sup = (iou > 0.5f) && (jg > ig);
        u64 w = __ballot(sup);
        if (lane == ip) my = w;
        cw |= sup ? (1ull << ip) : 0ull;
    }
    MT[(size_t)cj * N_BOXES + ig0 + lane] = my;
    int d = cj - ci;
    if (d <= 2) MT[tr_addr(d, jg)] = cw;
}

// ---------------- Phase C: sequential greedy reduce (1 block) ----------------
// wave0: ballot-fixpoint resolve per chunk, with chunks c-1/c-2 folded via
// prefetched transposed words. All 1024 threads: software-pipelined eager OR
// (issue iter c for y=c-1, commit iter c+1) into LDS removed words.
__global__ void __launch_bounds__(1024) nms_reduce_kernel(const u64* __restrict__ MT,
                                                          u64* __restrict__ keepw_g) {
    __shared__ unsigned rem32[NW * 2];
    __shared__ u64 keptw_lds[NW];
    int tid = threadIdx.x;
    for (int i = tid; i < NW * 2; i += 1024) rem32[i] = 0;
    __syncthreads();
    int wave = tid >> 6, lane = tid & 63;
    int wrel = tid >> 3, s = tid & 7;
    u64 acc = 0;                       // pipelined eager contribution
    u64 kept_m1 = 0, kept_m2 = 0;      // wave0: kept words of chunks c-1, c-2
    u64 td = 0, tf1 = 0, tf2 = 0;      // wave0: TR words for current chunk
    u64 ntd = 0, ntf1 = 0, ntf2 = 0;
    if (wave == 0) td = MT[tr_addr(0, lane)];   // chunk 0 diag suppressors
    for (int c = 0; c < NW; ++c) {
        if (wave == 0) {
            // prefetch TR words for chunk c+1 (used next iteration)
            if (c + 1 < NW) {
                int j = (c + 1) * 64 + lane;
                ntd  = MT[tr_addr(0, j)];
                ntf1 = MT[tr_addr(1, j)];
                ntf2 = (c + 1 >= 2) ? MT[tr_addr(2, j)] : 0ull;
            }
            u64 base = ((u64)rem32[2 * c + 1] << 32) | (u64)rem32[2 * c];
            bool er = ((tf1 & kept_m1) | (tf2 & kept_m2)) != 0ull;
            u64 R = base | __ballot(er);
            u64 K = 0, U = ~R;
            bool meU = (U >> lane) & 1;
            while (U) {
                u64 UK = U | K;
                u64 nK = __ballot(meU && ((td & UK) == 0ull));
                K |= nK;
                u64 nR = __ballot(meU && ((td & K) != 0ull));
                U &= ~(K | nR);
                meU = (U >> lane) & 1;
            }
            if (lane == 0) { keptw_lds[c] = K; keepw_g[c] = K; }
            kept_m2 = kept_m1; kept_m1 = K;
            td = ntd; tf1 = ntf1; tf2 = ntf2;
        }
        // commit previous iteration's eager loads (y = c-2, word = c+1+wrel)
        if (c >= 2) {
            int w = c + 1 + wrel;
            if (w < NW && acc) {
                atomicOr(&rem32[2 * w],     (unsigned)acc);
                atomicOr(&rem32[2 * w + 1], (unsigned)(acc >> 32));
            }
        }
        acc = 0;
        // issue eager loads for y = c-1 (word = c+2+wrel), commit next iter
        if (c >= 1) {
            int y = c - 1;
            int w = c + 2 + wrel;
            if (w < NW) {
                u64 ky = keptw_lds[y];
                const u64* col = MT + (size_t)w * N_BOXES + (size_t)y * 64;
                #pragma unroll
                for (int kk = 0; kk < 8; ++kk) {
                    int r = s + 8 * kk;
                    if ((ky >> r) & 1ull) acc |= col[r];
                }
            }
        }
        __syncthreads();
    }
}

// ---------------- Phase D: regression + masked output ----------------
__global__ void output_kernel(const float* __restrict__ bboxes,
                              const float* __restrict__ features,
                              const float* __restrict__ Wm, const float* __restrict__ bv,
                              const int* __restrict__ widthp, const int* __restrict__ heightp,
                              const u32* __restrict__ rank_of, const u64* __restrict__ keepw,
                              float* __restrict__ out) {
    int i = blockIdx.x * blockDim.x + threadIdx.x;
    if (i >= N_BOXES) return;
    u32 r = rank_of[i];
    float keep = (float)((keepw[r >> 6] >> (r & 63)) & 1ull);
    float z0 = bv[0], z1 = bv[1], z2 = bv[2], z3 = bv[3];
    #pragma unroll
    for (int m = 0; m < FEAT; ++m) {
        float f = features[i * FEAT + m];
        z0 += f * Wm[m * 4 + 0];
        z1 += f * Wm[m * 4 + 1];
        z2 += f * Wm[m * 4 + 2];
        z3 += f * Wm[m * 4 + 3];
    }
    float t0 = 1.0f / (1.0f + expf(-z0));
    float t1 = 1.0f / (1.0f + expf(-z1));
    float t2 = 1.0f / (1.0f + expf(-z2));
    float t3 = 1.0f / (1.0f + expf(-z3));
    float x = bboxes[4 * i + 0], y = bboxes[4 * i + 1];
    float w = bboxes[4 * i + 2], h = bboxes[4 * i + 3];
    float ox = fmaxf(t0 * w + x, 0.0f);
    float oy = fmaxf(t1 * h + y, 0.0f);
    float ow = w * expf(t2);
    float oh = h * expf(t3);
    float sw = (float)(*widthp), sh = (float)(*heightp);
    out[4 * i + 0] = ox * sw * keep;
    out[4 * i + 1] = oy * sh * keep;
    out[4 * i + 2] = ow * sw * keep;
    out[4 * i + 3] = oh * sh * keep;
}

extern "C" void kernel_launch(void* const* d_in, const int* in_sizes, int n_in,
                              void* d_out, int out_size, void* d_ws, size_t ws_size,
                              hipStream_t stream) {
    const float* bboxes   = (const float*)d_in[0];
    const float* scores   = (const float*)d_in[1];
    const float* features = (const float*)d_in[2];
    const float* Wm       = (const float*)d_in[3];
    const float* bv       = (const float*)d_in[4];
    const int*   widthp   = (const int*)d_in[5];
    const int*   heightp  = (const int*)d_in[6];
    float* out = (float*)d_out;

    char* ws = (char*)d_ws;
    u64* MT      = (u64*)ws;                                      // 8 MiB (incl. TR region)
    float* x1s   = (float*)(ws + (size_t)NW * N_BOXES * sizeof(u64));
    float* y1s   = x1s + N_BOXES;
    float* x2s   = y1s + N_BOXES;
    float* y2s   = x2s + N_BOXES;
    float* areas = y2s + N_BOXES;
    u32* rank_of = (u32*)(areas + N_BOXES);
    u64* keepw   = (u64*)(rank_of + N_BOXES);

    rank_scatter_kernel<<<N_BOXES / 32, 256, 0, stream>>>(bboxes, scores,
                                                          x1s, y1s, x2s, y2s, areas, rank_of);
    mask_kernel<<<dim3(NW, NW), 64, 0, stream>>>(x1s, y1s, x2s, y2s, areas, MT);
    nms_reduce_kernel<<<1, 1024, 0, stream>>>(MT, keepw);
    output_kernel<<<N_BOXES / 256, 256, 0, stream>>>(bboxes, features, Wm, bv,
                                                     widthp, heightp, rank_of, keepw, out);
}

// Round 3
// 193.321 us; speedup vs baseline: 2.3013x; 1.6915x over previous
//
#include <hip/hip_runtime.h>
#include <hip/hip_bf16.h>

#define N_BOXES 8192
#define NW 128            // number of 64-box chunks / 64-bit words per row
#define FEAT 10
#define SLOTS 4           // kept-box slots per wave (16 waves x 4 = 64 max kept/chunk)

typedef unsigned long long u64;
typedef unsigned int u32;

__device__ __forceinline__ void barrier_nodrain() {
    asm volatile("s_waitcnt lgkmcnt(0)" ::: "memory");
    __builtin_amdgcn_sched_barrier(0);
    __builtin_amdgcn_s_barrier();
    __builtin_amdgcn_sched_barrier(0);
    asm volatile("" ::: "memory");
}

// ---------------- Phase A: rank + scatter sorted boxes ----------------
// Descending-score order, ties broken by larger original index first
// (matches jnp.argsort(stable)[::-1]).
__global__ void rank_scatter_kernel(const float* __restrict__ bboxes,
                                    const float* __restrict__ scores,
                                    float* __restrict__ x1s, float* __restrict__ y1s,
                                    float* __restrict__ x2s, float* __restrict__ y2s,
                                    u32* __restrict__ rank_of) {
    __shared__ float sc[N_BOXES];
    int tid = threadIdx.x;
    for (int t = 0; t < N_BOXES / 256; ++t)
        sc[tid + 256 * t] = scores[tid + 256 * t];
    __syncthreads();
    int k = tid >> 3;          // box slot 0..31
    int s = tid & 7;           // segment 0..7
    int i = blockIdx.x * 32 + k;
    float si = sc[i];
    int cnt = 0;
    const float4* sc4 = (const float4*)sc;
    int q0 = s * (N_BOXES / 32);
    #pragma unroll 4
    for (int q = q0; q < q0 + N_BOXES / 32; ++q) {
        float4 v = sc4[q];
        int j = 4 * q;
        cnt += (int)((v.x > si) || (v.x == si && j     > i));
        cnt += (int)((v.y > si) || (v.y == si && j + 1 > i));
        cnt += (int)((v.z > si) || (v.z == si && j + 2 > i));
        cnt += (int)((v.w > si) || (v.w == si && j + 3 > i));
    }
    cnt += __shfl_down(cnt, 4, 8);
    cnt += __shfl_down(cnt, 2, 8);
    cnt += __shfl_down(cnt, 1, 8);
    if (s == 0) {
        int r = cnt;
        float x = bboxes[4 * i + 0], y = bboxes[4 * i + 1];
        float w = bboxes[4 * i + 2], h = bboxes[4 * i + 3];
        float x2 = x + w, y2 = y + h;           // exact ref op order
        x1s[r] = x; y1s[r] = y; x2s[r] = x2; y2s[r] = y2;
        rank_of[i] = (u32)r;
    }
}

// ---------------- Phase B: suppression bitmask matrix ----------------
// Row-major: RM[i*NW + cj] = word over j in chunk cj of sup(i->j) (j>i).
// TRb[d*N + j] (d=0,1,2) = word over i in chunk (chunk(j)-d) of sup(i->j).
// 4 waves/block, wave-private LDS slices, no block barrier needed.
__global__ void __launch_bounds__(256) mask_kernel(
        const float* __restrict__ x1s, const float* __restrict__ y1s,
        const float* __restrict__ x2s, const float* __restrict__ y2s,
        u64* __restrict__ RM, u64* __restrict__ TRb) {
    int wv = threadIdx.x >> 6, lane = threadIdx.x & 63;
    int ci = blockIdx.x;
    int cj = blockIdx.y * 4 + wv;
    if (cj < ci || cj >= NW) return;
    __shared__ float S[4][4][64];
    int d = cj - ci;
    int ig0 = ci * 64, jg0 = cj * 64;
    if (d <= 2) {
        // lanes = columns j; LDS = i-chunk; ballot loop gives row + column words
        S[wv][0][lane] = x1s[ig0 + lane];
        S[wv][1][lane] = y1s[ig0 + lane];
        S[wv][2][lane] = x2s[ig0 + lane];
        S[wv][3][lane] = y2s[ig0 + lane];
        int jg = jg0 + lane;
        float jx1 = x1s[jg], jy1 = y1s[jg], jx2 = x2s[jg], jy2 = y2s[jg];
        float jar = (jx2 - jx1) * (jy2 - jy1);   // bit-identical to ref area
        u64 my = 0, cw = 0;
        for (int ip = 0; ip < 64; ++ip) {
            float ix1 = S[wv][0][ip], iy1 = S[wv][1][ip];
            float ix2 = S[wv][2][ip], iy2 = S[wv][3][ip];
            float iar = (ix2 - ix1) * (iy2 - iy1);
            float xx1 = fmaxf(ix1, jx1);
            float yy1 = fmaxf(iy1, jy1);
            float xx2 = fminf(ix2, jx2);
            float yy2 = fminf(iy2, jy2);
            float iw = fmaxf(xx2 - xx1, 0.0f);
            float ih = fmaxf(yy2 - yy1, 0.0f);
            float inter = iw * ih;
            float uni = iar + jar - inter;
            float iou = __fdiv_rn(inter, uni);   // IEEE-exact like numpy
            bool sup = (iou > 0.5f) && (jg > ig0 + ip);
            u64 w = __ballot(sup);
            if (lane == ip) my = w;
            cw |= sup ? (1ull << ip) : 0ull;
        }
        RM[(size_t)(ig0 + lane) * NW + cj] = my;
        TRb[(size_t)d * N_BOXES + jg] = cw;
    } else {
        // lanes = rows i; LDS = j-chunk; direct row words, no ballots
        S[wv][0][lane] = x1s[jg0 + lane];
        S[wv][1][lane] = y1s[jg0 + lane];
        S[wv][2][lane] = x2s[jg0 + lane];
        S[wv][3][lane] = y2s[jg0 + lane];
        int ig = ig0 + lane;
        float ix1 = x1s[ig], iy1 = y1s[ig], ix2 = x2s[ig], iy2 = y2s[ig];
        float iar = (ix2 - ix1) * (iy2 - iy1);
        u64 my = 0;
        for (int jp = 0; jp < 64; ++jp) {
            float jx1 = S[wv][0][jp], jy1 = S[wv][1][jp];
            float jx2 = S[wv][2][jp], jy2 = S[wv][3][jp];
            float jar = (jx2 - jx1) * (jy2 - jy1);
            float xx1 = fmaxf(ix1, jx1);
            float yy1 = fmaxf(iy1, jy1);
            float xx2 = fminf(ix2, jx2);
            float yy2 = fminf(iy2, jy2);
            float iw = fmaxf(xx2 - xx1, 0.0f);
            float ih = fmaxf(yy2 - yy1, 0.0f);
            float inter = iw * ih;
            float uni = iar + jar - inter;
            float iou = __fdiv_rn(inter, uni);
            bool sup = (iou > 0.5f);             // cj>ci+2 => j>i always
            my |= sup ? (1ull << jp) : 0ull;
        }
        RM[(size_t)ig * NW + cj] = my;
    }
}

// ---------------- Phase C: sequential greedy reduce (1 block) ----------------
// Per iter c: commit stage-B rows (chunk c-2, words>=c+1, LDS atomicOr) in
// parallel with wave0's ballot-fixpoint on chunk c (TR folds cover chunks
// c-1/c-2); ONE raw barrier (lgkmcnt-only drain); then issue coalesced row
// loads for chunk c's kept boxes (words>=c+3) that stay in flight across
// barriers until committed at iter c+2. No global stores in the loop.
__global__ void __launch_bounds__(1024) nms_reduce_kernel(
        const u64* __restrict__ RM, const u64* __restrict__ TRb,
        u64* __restrict__ keepw_g) {
    __shared__ u32 rem32[NW * 2];
    __shared__ u64 keptw_lds[NW];
    __shared__ unsigned char klist[2][64];
    __shared__ int kcount[2];
    const int tid = threadIdx.x;
    const int wave = tid >> 6, lane = tid & 63;
    for (int i = tid; i < NW * 2; i += 1024) rem32[i] = 0;
    // wave0 TR state: (td,tf1,tf2)=chunk c, (pd,pf1,pf2)=chunk c+1
    u64 td = 0, tf1 = 0, tf2 = 0, pd = 0, pf1 = 0, pf2 = 0;
    u64 kept_m1 = 0, kept_m2 = 0;
    if (wave == 0) {
        td  = TRb[lane];
        pd  = TRb[64 + lane];
        pf1 = TRb[N_BOXES + 64 + lane];
        pf2 = 0;                      // chunk1 d=2 unwritten; masked by kept_m2=0
    }
    __syncthreads();

    u64 A0[SLOTS], A1[SLOTS], B0[SLOTS], B1[SLOTS];
    #pragma unroll
    for (int s2 = 0; s2 < SLOTS; ++s2) { A0[s2] = 0; A1[s2] = 0; B0[s2] = 0; B1[s2] = 0; }
    int Abase = -1, Bbase = -1;

    #pragma unroll 2
    for (int c = 0; c < NW; ++c) {
        // wave0: issue TR prefetch for chunk c+2 (2-deep pipeline)
        u64 l0 = 0, l1 = 0, l2 = 0;
        if (wave == 0 && c + 2 < NW) {
            int j = (c + 2) * 64 + lane;
            l0 = TRb[j];
            l1 = TRb[N_BOXES + j];
            l2 = TRb[2 * N_BOXES + j];
        }
        // step2: commit stage B (rows of chunk c-2) into words >= c+1
        if (Bbase >= 0) {
            u64 o0 = 0, o1 = 0;
            #pragma unroll
            for (int s2 = 0; s2 < SLOTS; ++s2) { o0 |= B0[s2]; o1 |= B1[s2]; }
            int w0 = Bbase + 2 * lane;
            if (w0 < NW && o0) {
                atomicOr(&rem32[2 * w0],     (u32)o0);
                atomicOr(&rem32[2 * w0 + 1], (u32)(o0 >> 32));
            }
            int w1 = w0 + 1;
            if (w1 < NW && o1) {
                atomicOr(&rem32[2 * w1],     (u32)o1);
                atomicOr(&rem32[2 * w1 + 1], (u32)(o1 >> 32));
            }
        }
        // step3: wave0 ballot-fixpoint for chunk c
        if (wave == 0) {
            u64 base = ((u64)rem32[2 * c + 1] << 32) | (u64)rem32[2 * c];
            bool er = ((tf1 & kept_m1) | (tf2 & kept_m2)) != 0ull;
            u64 R = base | __ballot(er);
            u64 K = 0, U = ~R;
            bool meU = (U >> lane) & 1;
            while (U) {
                u64 UK = U | K;
                u64 nK = __ballot(meU && ((td & UK) == 0ull));
                K |= nK;
                u64 nR = __ballot(meU && ((td & K) != 0ull));
                U &= ~(K | nR);
                meU = (U >> lane) & 1;
            }
            int pb = c & 1;
            bool iskept = (K >> lane) & 1;
            int rank = __popcll(K & ((1ull << lane) - 1ull));
            if (iskept) klist[pb][rank] = (unsigned char)lane;
            if (lane == 0) { kcount[pb] = __popcll(K); keptw_lds[c] = K; }
            kept_m2 = kept_m1; kept_m1 = K;
            td = pd; tf1 = pf1; tf2 = pf2;
            pd = l0; pf1 = l1; pf2 = l2;
        }
        barrier_nodrain();   // klist/kcount/commits visible; loads stay in flight
        // step5: rotate stages; issue row loads for chunk c's kept boxes
        #pragma unroll
        for (int s2 = 0; s2 < SLOTS; ++s2) { B0[s2] = A0[s2]; B1[s2] = A1[s2]; }
        Bbase = Abase;
        Abase = -1;
        int e = c + 3;
        int we = e & ~1;
        if (we < NW) {
            int pb = c & 1;
            int k = kcount[pb];
            if (k > 0) {
                Abase = we;
                int myw = we + 2 * lane;
                bool inr = (myw < NW);
                #pragma unroll
                for (int s2 = 0; s2 < SLOTS; ++s2) {
                    A0[s2] = 0; A1[s2] = 0;
                    int r = wave + 16 * s2;
                    if (r < k && inr) {
                        int bi = c * 64 + (int)klist[pb][r];
                        const u64* rp = RM + (size_t)bi * NW + myw;
                        A0[s2] = rp[0];
                        A1[s2] = rp[1];
                    }
                }
                if (lane == 0 && (e & 1)) {      // word we==e-1 covered by tf2 fold
                    #pragma unroll
                    for (int s2 = 0; s2 < SLOTS; ++s2) A0[s2] = 0;
                }
            }
        }
    }
    __syncthreads();
    if (tid < NW) keepw_g[tid] = keptw_lds[tid];
}

// ---------------- Phase D: regression + masked output ----------------
__global__ void output_kernel(const float* __restrict__ bboxes,
                              const float* __restrict__ features,
                              const float* __restrict__ Wm, const float* __restrict__ bv,
                              const int* __restrict__ widthp, const int* __restrict__ heightp,
                              const u32* __restrict__ rank_of, const u64* __restrict__ keepw,
                              float* __restrict__ out) {
    int i = blockIdx.x * blockDim.x + threadIdx.x;
    if (i >= N_BOXES) return;
    u32 r = rank_of[i];
    float keep = (float)((keepw[r >> 6] >> (r & 63)) & 1ull);
    float z0 = bv[0], z1 = bv[1], z2 = bv[2], z3 = bv[3];
    #pragma unroll
    for (int m = 0; m < FEAT; ++m) {
        float f = features[i * FEAT + m];
        z0 += f * Wm[m * 4 + 0];
        z1 += f * Wm[m * 4 + 1];
        z2 += f * Wm[m * 4 + 2];
        z3 += f * Wm[m * 4 + 3];
    }
    float t0 = 1.0f / (1.0f + expf(-z0));
    float t1 = 1.0f / (1.0f + expf(-z1));
    float t2 = 1.0f / (1.0f + expf(-z2));
    float t3 = 1.0f / (1.0f + expf(-z3));
    float x = bboxes[4 * i + 0], y = bboxes[4 * i + 1];
    float w = bboxes[4 * i + 2], h = bboxes[4 * i + 3];
    float ox = fmaxf(t0 * w + x, 0.0f);
    float oy = fmaxf(t1 * h + y, 0.0f);
    float ow = w * expf(t2);
    float oh = h * expf(t3);
    float sw = (float)(*widthp), sh = (float)(*heightp);
    out[4 * i + 0] = ox * sw * keep;
    out[4 * i + 1] = oy * sh * keep;
    out[4 * i + 2] = ow * sw * keep;
    out[4 * i + 3] = oh * sh * keep;
}

extern "C" void kernel_launch(void* const* d_in, const int* in_sizes, int n_in,
                              void* d_out, int out_size, void* d_ws, size_t ws_size,
                              hipStream_t stream) {
    const float* bboxes   = (const float*)d_in[0];
    const float* scores   = (const float*)d_in[1];
    const float* features = (const float*)d_in[2];
    const float* Wm       = (const float*)d_in[3];
    const float* bv       = (const float*)d_in[4];
    const int*   widthp   = (const int*)d_in[5];
    const int*   heightp  = (const int*)d_in[6];
    float* out = (float*)d_out;

    char* ws = (char*)d_ws;
    u64* RM      = (u64*)ws;                                       // 8 MiB
    u64* TRb     = (u64*)(ws + (size_t)N_BOXES * NW * sizeof(u64)); // 192 KiB
    float* x1s   = (float*)((char*)TRb + (size_t)3 * N_BOXES * sizeof(u64));
    float* y1s   = x1s + N_BOXES;
    float* x2s   = y1s + N_BOXES;
    float* y2s   = x2s + N_BOXES;
    u32* rank_of = (u32*)(y2s + N_BOXES);
    u64* keepw   = (u64*)(rank_of + N_BOXES);

    rank_scatter_kernel<<<N_BOXES / 32, 256, 0, stream>>>(bboxes, scores,
                                                          x1s, y1s, x2s, y2s, rank_of);
    mask_kernel<<<dim3(NW, NW / 4), 256, 0, stream>>>(x1s, y1s, x2s, y2s, RM, TRb);
    nms_reduce_kernel<<<1, 1024, 0, stream>>>(RM, TRb, keepw);
    output_kernel<<<N_BOXES / 256, 256, 0, stream>>>(bboxes, features, Wm, bv,
                                                     widthp, heightp, rank_of, keepw, out);
}

// Round 4
// 183.485 us; speedup vs baseline: 2.4247x; 1.0536x over previous
//
#include <hip/hip_runtime.h>
#include <hip/hip_bf16.h>

#define N_BOXES 8192
#define NW 128            // number of 64-box chunks / 64-bit words per row
#define FEAT 10
#define CMAX 14           // speculative candidate slots (7 worker waves x 2)

typedef unsigned long long u64;
typedef unsigned int u32;

__device__ __forceinline__ void barrier_nodrain() {
    asm volatile("s_waitcnt lgkmcnt(0)" ::: "memory");
    __builtin_amdgcn_sched_barrier(0);
    __builtin_amdgcn_s_barrier();
    __builtin_amdgcn_sched_barrier(0);
    asm volatile("" ::: "memory");
}

// ---------------- Phase A: rank + scatter sorted boxes ----------------
__global__ void rank_scatter_kernel(const float* __restrict__ bboxes,
                                    const float* __restrict__ scores,
                                    float* __restrict__ x1s, float* __restrict__ y1s,
                                    float* __restrict__ x2s, float* __restrict__ y2s,
                                    u32* __restrict__ rank_of) {
    __shared__ float sc[N_BOXES];
    int tid = threadIdx.x;
    for (int t = 0; t < N_BOXES / 256; ++t)
        sc[tid + 256 * t] = scores[tid + 256 * t];
    __syncthreads();
    int k = tid >> 3;          // box slot 0..31
    int s = tid & 7;           // segment 0..7
    int i = blockIdx.x * 32 + k;
    float si = sc[i];
    int cnt = 0;
    const float4* sc4 = (const float4*)sc;
    int q0 = s * (N_BOXES / 32);
    #pragma unroll 4
    for (int q = q0; q < q0 + N_BOXES / 32; ++q) {
        float4 v = sc4[q];
        int j = 4 * q;
        cnt += (int)((v.x > si) || (v.x == si && j     > i));
        cnt += (int)((v.y > si) || (v.y == si && j + 1 > i));
        cnt += (int)((v.z > si) || (v.z == si && j + 2 > i));
        cnt += (int)((v.w > si) || (v.w == si && j + 3 > i));
    }
    cnt += __shfl_down(cnt, 4, 8);
    cnt += __shfl_down(cnt, 2, 8);
    cnt += __shfl_down(cnt, 1, 8);
    if (s == 0) {
        int r = cnt;
        float x = bboxes[4 * i + 0], y = bboxes[4 * i + 1];
        float w = bboxes[4 * i + 2], h = bboxes[4 * i + 3];
        float x2 = x + w, y2 = y + h;           // exact ref op order
        x1s[r] = x; y1s[r] = y; x2s[r] = x2; y2s[r] = y2;
        rank_of[i] = (u32)r;
    }
}

// ---------------- Phase B: suppression bitmask matrix ----------------
// Row-major: RM[i*NW + cj] = word over j in chunk cj of sup(i->j) (j>i).
// TRb[d*N + j] (d=0,1) = word over i in chunk (chunk(j)-d) of sup(i->j).
__global__ void __launch_bounds__(256) mask_kernel(
        const float* __restrict__ x1s, const float* __restrict__ y1s,
        const float* __restrict__ x2s, const float* __restrict__ y2s,
        u64* __restrict__ RM, u64* __restrict__ TRb) {
    int wv = threadIdx.x >> 6, lane = threadIdx.x & 63;
    int ci = blockIdx.x;
    int cj = blockIdx.y * 4 + wv;
    if (cj < ci || cj >= NW) return;
    __shared__ float S[4][4][64];
    int d = cj - ci;
    int ig0 = ci * 64, jg0 = cj * 64;
    if (d <= 1) {
        // lanes = columns j; LDS = i-chunk; ballot loop gives row + column words
        S[wv][0][lane] = x1s[ig0 + lane];
        S[wv][1][lane] = y1s[ig0 + lane];
        S[wv][2][lane] = x2s[ig0 + lane];
        S[wv][3][lane] = y2s[ig0 + lane];
        int jg = jg0 + lane;
        float jx1 = x1s[jg], jy1 = y1s[jg], jx2 = x2s[jg], jy2 = y2s[jg];
        float jar = (jx2 - jx1) * (jy2 - jy1);   // bit-identical to ref area
        u64 my = 0, cw = 0;
        for (int ip = 0; ip < 64; ++ip) {
            float ix1 = S[wv][0][ip], iy1 = S[wv][1][ip];
            float ix2 = S[wv][2][ip], iy2 = S[wv][3][ip];
            float iar = (ix2 - ix1) * (iy2 - iy1);
            float xx1 = fmaxf(ix1, jx1);
            float yy1 = fmaxf(iy1, jy1);
            float xx2 = fminf(ix2, jx2);
            float yy2 = fminf(iy2, jy2);
            float iw = fmaxf(xx2 - xx1, 0.0f);
            float ih = fmaxf(yy2 - yy1, 0.0f);
            float inter = iw * ih;
            float uni = iar + jar - inter;
            float iou = __fdiv_rn(inter, uni);   // IEEE-exact like numpy
            bool sup = (iou > 0.5f) && (jg > ig0 + ip);
            u64 w = __ballot(sup);
            if (lane == ip) my = w;
            cw |= sup ? (1ull << ip) : 0ull;
        }
        RM[(size_t)(ig0 + lane) * NW + cj] = my;
        TRb[(size_t)d * N_BOXES + jg] = cw;
    } else {
        // lanes = rows i; LDS = j-chunk; direct row words, no ballots
        S[wv][0][lane] = x1s[jg0 + lane];
        S[wv][1][lane] = y1s[jg0 + lane];
        S[wv][2][lane] = x2s[jg0 + lane];
        S[wv][3][lane] = y2s[jg0 + lane];
        int ig = ig0 + lane;
        float ix1 = x1s[ig], iy1 = y1s[ig], ix2 = x2s[ig], iy2 = y2s[ig];
        float iar = (ix2 - ix1) * (iy2 - iy1);
        u64 my = 0;
        for (int jp = 0; jp < 64; ++jp) {
            float jx1 = S[wv][0][jp], jy1 = S[wv][1][jp];
            float jx2 = S[wv][2][jp], jy2 = S[wv][3][jp];
            float jar = (jx2 - jx1) * (jy2 - jy1);
            float xx1 = fmaxf(ix1, jx1);
            float yy1 = fmaxf(iy1, jy1);
            float xx2 = fminf(ix2, jx2);
            float yy2 = fminf(iy2, jy2);
            float iw = fmaxf(xx2 - xx1, 0.0f);
            float ih = fmaxf(yy2 - yy1, 0.0f);
            float inter = iw * ih;
            float uni = iar + jar - inter;
            float iou = __fdiv_rn(inter, uni);
            bool sup = (iou > 0.5f);             // cj>ci+1 => j>i always
            my |= sup ? (1ull << jp) : 0ull;
        }
        RM[(size_t)ig * NW + cj] = my;
    }
}

// ---------------- Phase C+D: greedy reduce (1 block) + fused output ---------
// Per region c (one barrier): wave0 runs the ballot-fixpoint for chunk c (TR
// planes in LDS; d=1 fold covers chunk c-1); wave1 publishes the candidate
// list for chunk c+1 (alive-superset from rem32); worker waves 1-7 issue
// speculative row loads for chunk c's candidates (held in regs across the
// barrier) and commit chunk c-1's kept rows (loaded last region) via full-row
// LDS atomicOr (past-word writes are benign). Output is computed in a fused
// tail from keptw in LDS.
__global__ void __launch_bounds__(512) nms_reduce_fused(
        const u64* __restrict__ RM, const u64* __restrict__ TRb,
        const u32* __restrict__ rank_of,
        const float* __restrict__ bboxes, const float* __restrict__ features,
        const float* __restrict__ Wm, const float* __restrict__ bv,
        const int* __restrict__ widthp, const int* __restrict__ heightp,
        float* __restrict__ out) {
    __shared__ u64 TR0L[N_BOXES];      // 64 KiB: diag suppressors
    __shared__ u64 TR1L[N_BOXES];      // 64 KiB: prev-chunk suppressors
    __shared__ u32 rem32[NW * 2];
    __shared__ u64 keptw[NW];
    __shared__ unsigned char clist[2][16];
    __shared__ u32 ccnt[2];
    __shared__ u64 ovmsk[2];

    const int tid = threadIdx.x;
    const int wv = tid >> 6, lane = tid & 63;

    #pragma unroll
    for (int k = 0; k < 16; ++k) {
        int idx = tid + 512 * k;
        TR0L[idx] = TRb[idx];
        TR1L[idx] = TRb[N_BOXES + idx];
    }
    if (tid < NW * 2) rem32[tid] = 0;
    if (wv == 1) {
        if (lane < CMAX) clist[0][lane] = (unsigned char)lane;
        if (lane == 0) { ccnt[0] = 64; ovmsk[0] = ~((1ull << CMAX) - 1ull); }
    }
    __syncthreads();

    u64 k_prev = 0;
    u64 Ah0 = 0, Ah1 = 0, Ah2 = 0, Ah3 = 0, Aov = 0; u32 Ab = 0, Anc = 0;
    u64 Bh0 = 0, Bh1 = 0, Bh2 = 0, Bh3 = 0, Bov = 0; u32 Bb = 0, Bnc = 0;

#define REGION(C, Ih0, Ih1, Ih2, Ih3, Iov, Ib, Inc, Ch0, Ch1, Ch2, Ch3, Cov, Cb, Cnc) \
    do {                                                                           \
        const int c_ = (C);                                                        \
        if (wv == 0) {                                                             \
            u64 td  = TR0L[c_ * 64 + lane];                                        \
            u64 tf1 = TR1L[c_ * 64 + lane];                                        \
            u64 base = ((u64)rem32[2 * c_ + 1] << 32) | (u64)rem32[2 * c_];        \
            u64 R = base | __ballot((tf1 & k_prev) != 0ull);                       \
            u64 K = 0, U = ~R;                                                     \
            bool meU = (U >> lane) & 1;                                            \
            while (U) {                                                            \
                u64 UK = U | K;                                                    \
                u64 nK = __ballot(meU && ((td & UK) == 0ull));                     \
                K |= nK;                                                           \
                u64 nR = __ballot(meU && ((td & K) != 0ull));                      \
                U &= ~(K | nR);                                                    \
                meU = (U >> lane) & 1;                                             \
            }                                                                      \
            if (lane == 0) keptw[c_] = K;                                          \
            k_prev = K;                                                            \
        } else {                                                                   \
            if (wv == 1 && c_ + 1 < NW) {                                          \
                int cn = c_ + 1;                                                   \
                u64 alive = ~(((u64)rem32[2 * cn + 1] << 32) | (u64)rem32[2 * cn]);\
                int rk = __popcll(alive & ((1ull << lane) - 1ull));                \
                bool al = (alive >> lane) & 1;                                     \
                if (al && rk < CMAX) clist[cn & 1][rk] = (unsigned char)lane;      \
                u64 ovm = __ballot(al && rk >= CMAX);                              \
                if (lane == 0) { ccnt[cn & 1] = (u32)__popcll(alive);              \
                                 ovmsk[cn & 1] = ovm; }                            \
            }                                                                      \
            /* ISSUE speculative rows for chunk c_ (consumed next region) */       \
            Ih0 = 0; Ih1 = 0; Ih2 = 0; Ih3 = 0;                                    \
            if (c_ != NW - 1) {                                                    \
                Inc = ccnt[c_ & 1];                                                \
                Iov = ovmsk[c_ & 1];                                               \
                Ib = (u32)(*(const unsigned short*)&clist[c_ & 1][(wv - 1) * 2]);  \
                int rc0 = (wv - 1) * 2;                                            \
                const u64* rowbase = RM + (size_t)c_ * 64 * NW;                    \
                if (rc0 < (int)Inc) {                                              \
                    const u64* rp = rowbase + (size_t)(Ib & 0xffu) * NW;           \
                    Ih0 = rp[lane]; Ih1 = rp[64 + lane];                           \
                }                                                                  \
                if (rc0 + 1 < (int)Inc) {                                          \
                    const u64* rp = rowbase + (size_t)(Ib >> 8) * NW;              \
                    Ih2 = rp[lane]; Ih3 = rp[64 + lane];                           \
                }                                                                  \
            } else { Inc = 0; Iov = 0; Ib = 0; }                                   \
            /* COMMIT chunk c_-1 kept rows (loaded last region) */                 \
            if (c_ > 0) {                                                          \
                u64 Kp = keptw[c_ - 1];                                            \
                int rc0 = (wv - 1) * 2;                                            \
                bool t0 = (rc0 < (int)Cnc) && ((Kp >> (Cb & 0xffu)) & 1ull);       \
                bool t1 = (rc0 + 1 < (int)Cnc) && ((Kp >> (Cb >> 8)) & 1ull);      \
                u64 s0 = (t0 ? Ch0 : 0ull) | (t1 ? Ch2 : 0ull);                    \
                u64 s1 = (t0 ? Ch1 : 0ull) | (t1 ? Ch3 : 0ull);                    \
                if (s0) { atomicOr(&rem32[2 * lane], (u32)s0);                     \
                          atomicOr(&rem32[2 * lane + 1], (u32)(s0 >> 32)); }       \
                if (s1) { atomicOr(&rem32[2 * (64 + lane)], (u32)s1);              \
                          atomicOr(&rem32[2 * (64 + lane) + 1], (u32)(s1 >> 32)); }\
                u64 ovk = Cov & Kp;                                                \
                if (ovk) {                                                         \
                    u64 mm = ovk;                                                  \
                    int skip = wv - 1;                                             \
                    for (int z = 0; z < skip; ++z) mm &= mm - 1;                   \
                    while (mm) {                                                   \
                        int b = __builtin_ctzll(mm);                               \
                        const u64* rp = RM + ((size_t)(c_ - 1) * 64 + b) * NW;     \
                        u64 r0 = rp[lane], r1 = rp[64 + lane];                     \
                        if (r0) { atomicOr(&rem32[2 * lane], (u32)r0);             \
                                  atomicOr(&rem32[2 * lane + 1], (u32)(r0 >> 32)); }\
                        if (r1) { atomicOr(&rem32[2 * (64 + lane)], (u32)r1);      \
                                  atomicOr(&rem32[2 * (64 + lane) + 1], (u32)(r1 >> 32)); }\
                        mm &= mm - 1; mm &= mm - 1; mm &= mm - 1; mm &= mm - 1;    \
                        mm &= mm - 1; mm &= mm - 1; mm &= mm - 1;                  \
                    }                                                              \
                }                                                                  \
            }                                                                      \
        }                                                                          \
        barrier_nodrain();                                                         \
    } while (0)

    for (int cc = 0; cc < NW; cc += 2) {
        REGION(cc,     Ah0, Ah1, Ah2, Ah3, Aov, Ab, Anc,
                       Bh0, Bh1, Bh2, Bh3, Bov, Bb, Bnc);
        REGION(cc + 1, Bh0, Bh1, Bh2, Bh3, Bov, Bb, Bnc,
                       Ah0, Ah1, Ah2, Ah3, Aov, Ab, Anc);
    }
#undef REGION

    __syncthreads();

    // ---------------- fused output tail ----------------
    float wreg[FEAT * 4];
    #pragma unroll
    for (int m = 0; m < FEAT * 4; ++m) wreg[m] = Wm[m];
    float bb0 = bv[0], bb1 = bv[1], bb2 = bv[2], bb3 = bv[3];
    float sw = (float)(*widthp), sh = (float)(*heightp);
    for (int k = 0; k < N_BOXES / 512; ++k) {
        int i = tid + 512 * k;
        u32 r = rank_of[i];
        float keep = (float)((keptw[r >> 6] >> (r & 63)) & 1ull);
        float z0 = bb0, z1 = bb1, z2 = bb2, z3 = bb3;
        #pragma unroll
        for (int m = 0; m < FEAT; ++m) {
            float f = features[i * FEAT + m];
            z0 += f * wreg[m * 4 + 0];
            z1 += f * wreg[m * 4 + 1];
            z2 += f * wreg[m * 4 + 2];
            z3 += f * wreg[m * 4 + 3];
        }
        float t0 = 1.0f / (1.0f + expf(-z0));
        float t1 = 1.0f / (1.0f + expf(-z1));
        float t2 = 1.0f / (1.0f + expf(-z2));
        float t3 = 1.0f / (1.0f + expf(-z3));
        float4 bx = ((const float4*)bboxes)[i];
        float ox = fmaxf(t0 * bx.z + bx.x, 0.0f);
        float oy = fmaxf(t1 * bx.w + bx.y, 0.0f);
        float ow = bx.z * expf(t2);
        float oh = bx.w * expf(t3);
        float4 o;
        o.x = ox * sw * keep;
        o.y = oy * sh * keep;
        o.z = ow * sw * keep;
        o.w = oh * sh * keep;
        ((float4*)out)[i] = o;
    }
}

extern "C" void kernel_launch(void* const* d_in, const int* in_sizes, int n_in,
                              void* d_out, int out_size, void* d_ws, size_t ws_size,
                              hipStream_t stream) {
    const float* bboxes   = (const float*)d_in[0];
    const float* scores   = (const float*)d_in[1];
    const float* features = (const float*)d_in[2];
    const float* Wm       = (const float*)d_in[3];
    const float* bv       = (const float*)d_in[4];
    const int*   widthp   = (const int*)d_in[5];
    const int*   heightp  = (const int*)d_in[6];
    float* out = (float*)d_out;

    char* ws = (char*)d_ws;
    u64* RM      = (u64*)ws;                                        // 8 MiB
    u64* TRb     = (u64*)(ws + (size_t)N_BOXES * NW * sizeof(u64)); // 128 KiB
    float* x1s   = (float*)((char*)TRb + (size_t)2 * N_BOXES * sizeof(u64));
    float* y1s   = x1s + N_BOXES;
    float* x2s   = y1s + N_BOXES;
    float* y2s   = x2s + N_BOXES;
    u32* rank_of = (u32*)(y2s + N_BOXES);

    rank_scatter_kernel<<<N_BOXES / 32, 256, 0, stream>>>(bboxes, scores,
                                                          x1s, y1s, x2s, y2s, rank_of);
    mask_kernel<<<dim3(NW, NW / 4), 256, 0, stream>>>(x1s, y1s, x2s, y2s, RM, TRb);
    nms_reduce_fused<<<1, 512, 0, stream>>>(RM, TRb, rank_of, bboxes, features,
                                            Wm, bv, widthp, heightp, out);
}